// Round 3
// baseline (131.585 us; speedup 1.0000x reference)
//
#include <hip/hip_runtime.h>

#define BATCH 16384
#define DIM   512
#define NCLS  2048

typedef _Float16 half8 __attribute__((ext_vector_type(8)));
typedef float    floatx4 __attribute__((ext_vector_type(4)));

#define GLB(p) ((const __attribute__((address_space(1))) void*)(p))
#define LDSP(p) ((__attribute__((address_space(3))) void*)(p))

// ---------------- fp32 -> fp16 convert (8 elems/thread) ----------------
__global__ __launch_bounds__(256) void cvt_kernel(const float* __restrict__ src,
                                                  _Float16* __restrict__ dst) {
    size_t i = ((size_t)blockIdx.x * 256 + threadIdx.x) * 8;
    float4 a = *reinterpret_cast<const float4*>(src + i);
    float4 b = *reinterpret_cast<const float4*>(src + i + 4);
    half8 h;
    h[0] = (_Float16)a.x; h[1] = (_Float16)a.y; h[2] = (_Float16)a.z; h[3] = (_Float16)a.w;
    h[4] = (_Float16)b.x; h[5] = (_Float16)b.y; h[6] = (_Float16)b.z; h[7] = (_Float16)b.w;
    *reinterpret_cast<half8*>(dst + i) = h;
}

// ---------------- 0.5 * ||c_k||^2, one wave per class ----------------
__global__ __launch_bounds__(64) void csq_kernel(const float* __restrict__ c,
                                                 float* __restrict__ hcsq) {
    int k = blockIdx.x, t = threadIdx.x;
    const float4* p = reinterpret_cast<const float4*>(c + (size_t)k * DIM);
    float s = 0.f;
    #pragma unroll
    for (int j = 0; j < 2; ++j) {
        float4 v = p[t + j * 64];
        s += v.x * v.x + v.y * v.y + v.z * v.z + v.w * v.w;
    }
    #pragma unroll
    for (int o = 32; o; o >>= 1) s += __shfl_xor(s, o);
    if (t == 0) hcsq[k] = 0.5f * s;
}

// ---------------- fused GEMM + softmax ----------------
// Block: 512 threads (8 waves), M_TILE = 32 rows, full N = 2048 in 8 chunks of 256.
// Wave w: row-tile rt = w&1 (16 rows), col-group cg = w>>1 (64 cols/chunk).
// Logits kept fp32 in registers: logv[8 chunks][4 ct] floatx4 = 128 regs/lane.
// K-loop is T3 minimum-2-phase: stage(t+1) -> ds_read buf[t] -> MFMA -> ONE barrier
// (vmcnt(0) drain sits AFTER compute, overlapping prefetch latency with work).
__global__ __launch_bounds__(512, 2) void fused_kernel(
    const float* __restrict__ X,       // [BATCH][DIM] fp32
    const _Float16* __restrict__ Bh,   // [NCLS][DIM] fp16
    const float* __restrict__ hcsq,    // [NCLS] 0.5*||c||^2
    float* __restrict__ O)             // [BATCH][NCLS]
{
    __shared__ __align__(16) _Float16 As[32 * 512];        // 32 KB, swizzled granules
    __shared__ __align__(16) _Float16 Bs[2][256 * 64];     // 2 x 32 KB, swizzled granules
    __shared__ float redm[4][32];
    __shared__ float reds[4][32];

    const int tid  = threadIdx.x;
    const int lane = tid & 63;
    const int wave = tid >> 6;
    const int rt   = wave & 1;
    const int cg   = wave >> 1;
    const int rowB = blockIdx.x * 32;

    // ---- stage A once: fp32 -> fp16 with XOR-swizzled ds_write ----
    // granule = 16B = 8 halves; LDS(row, g) holds src(row, g ^ (row&7))
    #pragma unroll
    for (int i = 0; i < 4; ++i) {
        int G = i * 512 + tid;              // 2048 granules total
        int row = G >> 6, g = G & 63;
        const float* src = X + (size_t)(rowB + row) * DIM + g * 8;
        float4 a = *reinterpret_cast<const float4*>(src);
        float4 b = *reinterpret_cast<const float4*>(src + 4);
        half8 h;
        h[0] = (_Float16)a.x; h[1] = (_Float16)a.y; h[2] = (_Float16)a.z; h[3] = (_Float16)a.w;
        h[4] = (_Float16)b.x; h[5] = (_Float16)b.y; h[6] = (_Float16)b.z; h[7] = (_Float16)b.w;
        int dg = row * 64 + (g ^ (row & 7));
        *reinterpret_cast<half8*>(&As[dg * 8]) = h;
    }

    // ---- B staging: [256 cols][64 k] fp16, source-pre-swizzled for linear LDS dest ----
    // LDS(col, gb) holds Bh(col, gb ^ (col&7)); 4 x global_load_lds(16B) per wave
    auto stage_b = [&](int c2, int k2, int buf) {
        const int lcol = lane >> 3;                    // 0..7
        const int sw   = (lane & 7) ^ lcol;            // source granule xor
        #pragma unroll
        for (int i = 0; i < 4; ++i) {
            const int col = wave * 32 + i * 8 + lcol;
            const _Float16* src = Bh + (size_t)(c2 * 256 + col) * DIM + k2 * 64 + sw * 8;
            _Float16* dst = &Bs[buf][(wave * 4 + i) * 512];
            __builtin_amdgcn_global_load_lds(GLB(src), LDSP(dst), 16, 0, 0);
        }
    };

    stage_b(0, 0, 0);
    __syncthreads();   // drains vmcnt(0): buf0 ready; also covers A staging

    floatx4 acc[4] = {};
    floatx4 logv[8][4];
    float hc[4];

    #pragma unroll
    for (int chunk = 0; chunk < 8; ++chunk) {
        // prefetch 0.5*csq for this chunk's cols (consumed at chunk epilogue)
        #pragma unroll
        for (int ct = 0; ct < 4; ++ct)
            hc[ct] = hcsq[chunk * 256 + cg * 64 + ct * 16 + (lane & 15)];

        #pragma unroll
        for (int ks = 0; ks < 8; ++ks) {
            const int t = chunk * 8 + ks;
            // phase 1: issue next-tile prefetch (in flight across compute below)
            if (t < 63) {
                const int tn = t + 1;
                stage_b(tn >> 3, tn & 7, tn & 1);
            }
            // phase 2: compute on buf[t&1] — ready since previous step's barrier
            const int buf = t & 1;
            #pragma unroll
            for (int k2 = 0; k2 < 2; ++k2) {
                const int arow = rt * 16 + (lane & 15);
                const int ag   = ks * 8 + k2 * 4 + (lane >> 4);
                half8 af = *reinterpret_cast<const half8*>(
                    &As[arow * 512 + (ag ^ (lane & 7)) * 8]);
                #pragma unroll
                for (int ct = 0; ct < 4; ++ct) {
                    const int bcol = cg * 64 + ct * 16 + (lane & 15);
                    const int bg   = k2 * 4 + (lane >> 4);
                    half8 bf = *reinterpret_cast<const half8*>(
                        &Bs[buf][bcol * 64 + (bg ^ (lane & 7)) * 8]);
                    acc[ct] = __builtin_amdgcn_mfma_f32_16x16x32_f16(af, bf, acc[ct], 0, 0, 0);
                }
            }
            // single barrier per step: vmcnt(0) drain lands AFTER compute, so the
            // stage(t+1) latency overlapped the ds_reads+MFMAs above. Also ensures
            // all waves' reads of buf[t] are done before t+2 overwrites it.
            __syncthreads();
        }
        // chunk epilogue: logits = cross - 0.5*csq, reset acc
        #pragma unroll
        for (int ct = 0; ct < 4; ++ct) {
            floatx4 v = acc[ct];
            v[0] -= hc[ct]; v[1] -= hc[ct]; v[2] -= hc[ct]; v[3] -= hc[ct];
            logv[chunk][ct] = v;
            acc[ct] = (floatx4){0.f, 0.f, 0.f, 0.f};
        }
    }

    // ---- softmax finalize ----
    float mj[4] = {-1e30f, -1e30f, -1e30f, -1e30f};
    #pragma unroll
    for (int c = 0; c < 8; ++c)
        #pragma unroll
        for (int ct = 0; ct < 4; ++ct)
            #pragma unroll
            for (int j = 0; j < 4; ++j)
                mj[j] = fmaxf(mj[j], logv[c][ct][j]);
    #pragma unroll
    for (int off = 8; off >= 1; off >>= 1)
        #pragma unroll
        for (int j = 0; j < 4; ++j)
            mj[j] = fmaxf(mj[j], __shfl_xor(mj[j], off));
    if ((lane & 15) == 0) {
        #pragma unroll
        for (int j = 0; j < 4; ++j)
            redm[cg][rt * 16 + (lane >> 4) * 4 + j] = mj[j];
    }
    __syncthreads();

    float M[4];
    #pragma unroll
    for (int j = 0; j < 4; ++j) {
        const int row = rt * 16 + (lane >> 4) * 4 + j;
        M[j] = fmaxf(fmaxf(redm[0][row], redm[1][row]),
                     fmaxf(redm[2][row], redm[3][row]));
    }

    float sj[4] = {0.f, 0.f, 0.f, 0.f};
    #pragma unroll
    for (int c = 0; c < 8; ++c)
        #pragma unroll
        for (int ct = 0; ct < 4; ++ct)
            #pragma unroll
            for (int j = 0; j < 4; ++j) {
                float e = __expf(logv[c][ct][j] - M[j]);
                logv[c][ct][j] = e;
                sj[j] += e;
            }
    #pragma unroll
    for (int off = 8; off >= 1; off >>= 1)
        #pragma unroll
        for (int j = 0; j < 4; ++j)
            sj[j] += __shfl_xor(sj[j], off);
    if ((lane & 15) == 0) {
        #pragma unroll
        for (int j = 0; j < 4; ++j)
            reds[cg][rt * 16 + (lane >> 4) * 4 + j] = sj[j];
    }
    __syncthreads();

    float inv[4];
    #pragma unroll
    for (int j = 0; j < 4; ++j) {
        const int row = rt * 16 + (lane >> 4) * 4 + j;
        inv[j] = 1.0f / (reds[0][row] + reds[1][row] + reds[2][row] + reds[3][row]);
    }

    // ---- single write of normalized output ----
    #pragma unroll
    for (int c = 0; c < 8; ++c)
        #pragma unroll
        for (int ct = 0; ct < 4; ++ct) {
            const int col = c * 256 + cg * 64 + ct * 16 + (lane & 15);
            float* op = O + (size_t)(rowB + rt * 16 + (lane >> 4) * 4) * NCLS + col;
            #pragma unroll
            for (int j = 0; j < 4; ++j)
                op[(size_t)j * NCLS] = logv[c][ct][j] * inv[j];
        }
}

extern "C" void kernel_launch(void* const* d_in, const int* in_sizes, int n_in,
                              void* d_out, int out_size, void* d_ws, size_t ws_size,
                              hipStream_t stream) {
    const float* x       = (const float*)d_in[0];
    const float* centers = (const float*)d_in[1];
    float* out = (float*)d_out;

    // ws layout: c_fp16 [NCLS*DIM] (2 MB) | 0.5*csq [NCLS] (8 KB)
    _Float16* ch = (_Float16*)d_ws;
    float* hcsq  = (float*)(ch + (size_t)NCLS * DIM);

    hipLaunchKernelGGL(cvt_kernel, dim3(NCLS * DIM / (8 * 256)), dim3(256), 0, stream,
                       centers, ch);
    hipLaunchKernelGGL(csq_kernel, dim3(NCLS), dim3(64), 0, stream, centers, hcsq);
    hipLaunchKernelGGL(fused_kernel, dim3(BATCH / 32), dim3(512), 0, stream,
                       x, ch, hcsq, out);
}

// Round 4
// 118.511 us; speedup vs baseline: 1.1103x; 1.1103x over previous
//
#include <hip/hip_runtime.h>

#define BATCH 16384
#define DIM   512
#define NCLS  2048

typedef _Float16 half8 __attribute__((ext_vector_type(8)));
typedef float    floatx4 __attribute__((ext_vector_type(4)));

#define GLB(p) ((const __attribute__((address_space(1))) void*)(p))
#define LDSP(p) ((__attribute__((address_space(3))) void*)(p))

// ---------------- fp32 -> fp16 convert (8 elems/thread) ----------------
__global__ __launch_bounds__(256) void cvt_kernel(const float* __restrict__ src,
                                                  _Float16* __restrict__ dst) {
    size_t i = ((size_t)blockIdx.x * 256 + threadIdx.x) * 8;
    float4 a = *reinterpret_cast<const float4*>(src + i);
    float4 b = *reinterpret_cast<const float4*>(src + i + 4);
    half8 h;
    h[0] = (_Float16)a.x; h[1] = (_Float16)a.y; h[2] = (_Float16)a.z; h[3] = (_Float16)a.w;
    h[4] = (_Float16)b.x; h[5] = (_Float16)b.y; h[6] = (_Float16)b.z; h[7] = (_Float16)b.w;
    *reinterpret_cast<half8*>(dst + i) = h;
}

// ---------------- 0.5 * ||c_k||^2, one wave per class ----------------
__global__ __launch_bounds__(64) void csq_kernel(const float* __restrict__ c,
                                                 float* __restrict__ hcsq) {
    int k = blockIdx.x, t = threadIdx.x;
    const float4* p = reinterpret_cast<const float4*>(c + (size_t)k * DIM);
    float s = 0.f;
    #pragma unroll
    for (int j = 0; j < 2; ++j) {
        float4 v = p[t + j * 64];
        s += v.x * v.x + v.y * v.y + v.z * v.z + v.w * v.w;
    }
    #pragma unroll
    for (int o = 32; o; o >>= 1) s += __shfl_xor(s, o);
    if (t == 0) hcsq[k] = 0.5f * s;
}

// ---------------- fused GEMM + softmax ----------------
// Block: 512 threads (8 waves), M_TILE = 32 rows, N = 2048 in 8 chunks of 256.
// Wave w: row-tile rt = w&1 (16 rows), col-group cg = w>>1 (64 cols/chunk).
// K-loop: T4 counted-vmcnt pipeline, 3 B-buffers, ONE raw s_barrier per step:
//   vmcnt(4) -> s_barrier -> stage(t+2) -> [setprio(1) ds_read+MFMA setprio(0)]
// Stage latency stays in flight across barriers (never drained to 0 mid-loop).
__global__ __launch_bounds__(512, 2) void fused_kernel(
    const float* __restrict__ X,       // [BATCH][DIM] fp32
    const _Float16* __restrict__ Bh,   // [NCLS][DIM] fp16
    const float* __restrict__ hcsq,    // [NCLS] 0.5*||c||^2
    float* __restrict__ O)             // [BATCH][NCLS]
{
    __shared__ __align__(16) _Float16 As[32 * 512];        // 32 KB, swizzled granules
    __shared__ __align__(16) _Float16 Bs[3][256 * 64];     // 3 x 32 KB, swizzled granules
    __shared__ float redm[4][32];
    __shared__ float reds[4][32];

    const int tid  = threadIdx.x;
    const int lane = tid & 63;
    const int wave = tid >> 6;
    const int rt   = wave & 1;
    const int cg   = wave >> 1;
    const int rowB = blockIdx.x * 32;

    // ---- stage A once: fp32 -> fp16 with XOR-swizzled ds_write ----
    // granule = 16B = 8 halves; LDS(row, g) holds src(row, g ^ (row&7))
    #pragma unroll
    for (int i = 0; i < 4; ++i) {
        int G = i * 512 + tid;              // 2048 granules total
        int row = G >> 6, g = G & 63;
        const float* src = X + (size_t)(rowB + row) * DIM + g * 8;
        float4 a = *reinterpret_cast<const float4*>(src);
        float4 b = *reinterpret_cast<const float4*>(src + 4);
        half8 h;
        h[0] = (_Float16)a.x; h[1] = (_Float16)a.y; h[2] = (_Float16)a.z; h[3] = (_Float16)a.w;
        h[4] = (_Float16)b.x; h[5] = (_Float16)b.y; h[6] = (_Float16)b.z; h[7] = (_Float16)b.w;
        int dg = row * 64 + (g ^ (row & 7));
        *reinterpret_cast<half8*>(&As[dg * 8]) = h;
    }

    // ---- B staging: tile s covers cols (s>>3)*256..+256, k (s&7)*64..+64 ----
    // LDS(col, gb) holds Bh(col, gb ^ (col&7)); 4 x global_load_lds(16B) per wave
    auto stage_b = [&](int s) {
        const int c2 = s >> 3, k2 = s & 7, buf = s % 3;
        const int lcol = lane >> 3;                    // 0..7
        const int sw   = (lane & 7) ^ lcol;            // source granule xor
        #pragma unroll
        for (int i = 0; i < 4; ++i) {
            const int col = wave * 32 + i * 8 + lcol;
            const _Float16* src = Bh + (size_t)(c2 * 256 + col) * DIM + k2 * 64 + sw * 8;
            _Float16* dst = &Bs[buf][(wave * 4 + i) * 512];
            __builtin_amdgcn_global_load_lds(GLB(src), LDSP(dst), 16, 0, 0);
        }
    };

    // prologue: 2 tiles in flight; drain LDS writes (A) then publish
    stage_b(0);
    stage_b(1);
    asm volatile("s_waitcnt lgkmcnt(0)" ::: "memory");
    __builtin_amdgcn_s_barrier();

    floatx4 acc[4] = {};
    floatx4 logv[8][4];
    float hc[4];

    #pragma unroll
    for (int chunk = 0; chunk < 8; ++chunk) {
        // 0.5*csq for this chunk's cols (consumed at chunk epilogue; these 4
        // global loads enter the vmcnt queue -> counted waits below over-wait
        // slightly at chunk tops, which is safe)
        #pragma unroll
        for (int ct = 0; ct < 4; ++ct)
            hc[ct] = hcsq[chunk * 256 + cg * 64 + ct * 16 + (lane & 15)];

        #pragma unroll
        for (int ks = 0; ks < 8; ++ks) {
            const int t = chunk * 8 + ks;
            // counted wait: my stage(t) loads retired; stage(t+1) stays in flight
            if (t < 63) asm volatile("s_waitcnt vmcnt(4)" ::: "memory");
            else        asm volatile("s_waitcnt vmcnt(0)" ::: "memory");
            // publish: all waves' stage(t) landed AND all waves done with tile t-1
            __builtin_amdgcn_s_barrier();
            // refill the buffer tile t-1 occupied (freed by the barrier above)
            if (t + 2 < 64) stage_b(t + 2);

            const int buf = t % 3;
            __builtin_amdgcn_s_setprio(1);
            #pragma unroll
            for (int k2 = 0; k2 < 2; ++k2) {
                const int arow = rt * 16 + (lane & 15);
                const int ag   = ks * 8 + k2 * 4 + (lane >> 4);
                half8 af = *reinterpret_cast<const half8*>(
                    &As[arow * 512 + (ag ^ (lane & 7)) * 8]);
                #pragma unroll
                for (int ct = 0; ct < 4; ++ct) {
                    const int bcol = cg * 64 + ct * 16 + (lane & 15);
                    const int bg   = k2 * 4 + (lane >> 4);
                    half8 bf = *reinterpret_cast<const half8*>(
                        &Bs[buf][bcol * 64 + (bg ^ (lane & 7)) * 8]);
                    acc[ct] = __builtin_amdgcn_mfma_f32_16x16x32_f16(af, bf, acc[ct], 0, 0, 0);
                }
            }
            __builtin_amdgcn_s_setprio(0);
        }
        // chunk epilogue: logits = cross - 0.5*csq, reset acc
        #pragma unroll
        for (int ct = 0; ct < 4; ++ct) {
            floatx4 v = acc[ct];
            v[0] -= hc[ct]; v[1] -= hc[ct]; v[2] -= hc[ct]; v[3] -= hc[ct];
            logv[chunk][ct] = v;
            acc[ct] = (floatx4){0.f, 0.f, 0.f, 0.f};
        }
    }

    // ---- softmax finalize ----
    float mj[4] = {-1e30f, -1e30f, -1e30f, -1e30f};
    #pragma unroll
    for (int c = 0; c < 8; ++c)
        #pragma unroll
        for (int ct = 0; ct < 4; ++ct)
            #pragma unroll
            for (int j = 0; j < 4; ++j)
                mj[j] = fmaxf(mj[j], logv[c][ct][j]);
    #pragma unroll
    for (int off = 8; off >= 1; off >>= 1)
        #pragma unroll
        for (int j = 0; j < 4; ++j)
            mj[j] = fmaxf(mj[j], __shfl_xor(mj[j], off));
    if ((lane & 15) == 0) {
        #pragma unroll
        for (int j = 0; j < 4; ++j)
            redm[cg][rt * 16 + (lane >> 4) * 4 + j] = mj[j];
    }
    __syncthreads();

    float M[4];
    #pragma unroll
    for (int j = 0; j < 4; ++j) {
        const int row = rt * 16 + (lane >> 4) * 4 + j;
        M[j] = fmaxf(fmaxf(redm[0][row], redm[1][row]),
                     fmaxf(redm[2][row], redm[3][row]));
    }

    float sj[4] = {0.f, 0.f, 0.f, 0.f};
    #pragma unroll
    for (int c = 0; c < 8; ++c)
        #pragma unroll
        for (int ct = 0; ct < 4; ++ct)
            #pragma unroll
            for (int j = 0; j < 4; ++j) {
                float e = __expf(logv[c][ct][j] - M[j]);
                logv[c][ct][j] = e;
                sj[j] += e;
            }
    #pragma unroll
    for (int off = 8; off >= 1; off >>= 1)
        #pragma unroll
        for (int j = 0; j < 4; ++j)
            sj[j] += __shfl_xor(sj[j], off);
    if ((lane & 15) == 0) {
        #pragma unroll
        for (int j = 0; j < 4; ++j)
            reds[cg][rt * 16 + (lane >> 4) * 4 + j] = sj[j];
    }
    __syncthreads();

    float inv[4];
    #pragma unroll
    for (int j = 0; j < 4; ++j) {
        const int row = rt * 16 + (lane >> 4) * 4 + j;
        inv[j] = 1.0f / (reds[0][row] + reds[1][row] + reds[2][row] + reds[3][row]);
    }

    // ---- single write of normalized output ----
    #pragma unroll
    for (int c = 0; c < 8; ++c)
        #pragma unroll
        for (int ct = 0; ct < 4; ++ct) {
            const int col = c * 256 + cg * 64 + ct * 16 + (lane & 15);
            float* op = O + (size_t)(rowB + rt * 16 + (lane >> 4) * 4) * NCLS + col;
            #pragma unroll
            for (int j = 0; j < 4; ++j)
                op[(size_t)j * NCLS] = logv[c][ct][j] * inv[j];
        }
}

extern "C" void kernel_launch(void* const* d_in, const int* in_sizes, int n_in,
                              void* d_out, int out_size, void* d_ws, size_t ws_size,
                              hipStream_t stream) {
    const float* x       = (const float*)d_in[0];
    const float* centers = (const float*)d_in[1];
    float* out = (float*)d_out;

    // ws layout: c_fp16 [NCLS*DIM] (2 MB) | 0.5*csq [NCLS] (8 KB)
    _Float16* ch = (_Float16*)d_ws;
    float* hcsq  = (float*)(ch + (size_t)NCLS * DIM);

    hipLaunchKernelGGL(cvt_kernel, dim3(NCLS * DIM / (8 * 256)), dim3(256), 0, stream,
                       centers, ch);
    hipLaunchKernelGGL(csq_kernel, dim3(NCLS), dim3(64), 0, stream, centers, hcsq);
    hipLaunchKernelGGL(fused_kernel, dim3(BATCH / 32), dim3(512), 0, stream,
                       x, ch, hcsq, out);
}

// Round 7
// 110.854 us; speedup vs baseline: 1.1870x; 1.0691x over previous
//
#include <hip/hip_runtime.h>

#define BATCH 16384
#define DIM   512
#define NCLS  2048

typedef _Float16 half8 __attribute__((ext_vector_type(8)));
typedef float    floatx4 __attribute__((ext_vector_type(4)));

// ---------------- pack centers into 16x16x32 MFMA B-fragment order ----------------
// Granule t = (n*16 + s)*64 + lane  holds  C[n*16 + (lane&15)][s*32 + (lane>>4)*8 .. +8]
// (n = 16-col block, s = 32-deep K step) so a wave's B-fragment load is one
// contiguous 16B-aligned 1KB global_load_dwordx4. Matches the R1-verified 16x16x32
// B mapping: lane l holds col=(l&15), k=(l>>4)*8..+8.
__global__ __launch_bounds__(256) void pack_b(const float* __restrict__ C,
                                              _Float16* __restrict__ BP) {
    int t = blockIdx.x * 256 + threadIdx.x;   // [0, 128*16*64)
    int lane = t & 63, ns = t >> 6;
    int s = ns & 15, n = ns >> 4;
    int col = n * 16 + (lane & 15);
    int k   = s * 32 + (lane >> 4) * 8;
    const float4* src = reinterpret_cast<const float4*>(C + (size_t)col * DIM + k);
    float4 a = src[0], b = src[1];
    half8 h;
    h[0] = (_Float16)a.x; h[1] = (_Float16)a.y; h[2] = (_Float16)a.z; h[3] = (_Float16)a.w;
    h[4] = (_Float16)b.x; h[5] = (_Float16)b.y; h[6] = (_Float16)b.z; h[7] = (_Float16)b.w;
    *reinterpret_cast<half8*>(BP + (size_t)t * 8) = h;
}

// ---------------- 0.5 * ||c_k||^2, one wave per class ----------------
__global__ __launch_bounds__(64) void csq_kernel(const float* __restrict__ c,
                                                 float* __restrict__ hcsq) {
    int k = blockIdx.x, t = threadIdx.x;
    const float4* p = reinterpret_cast<const float4*>(c + (size_t)k * DIM);
    float s = 0.f;
    #pragma unroll
    for (int j = 0; j < 2; ++j) {
        float4 v = p[t + j * 64];
        s += v.x * v.x + v.y * v.y + v.z * v.z + v.w * v.w;
    }
    #pragma unroll
    for (int o = 32; o; o >>= 1) s += __shfl_xor(s, o);
    if (t == 0) hcsq[k] = 0.5f * s;
}

// ---------------- fused GEMM + softmax, zero-barrier K-loop ----------------
// 256 persistent blocks x 512 thr (8 waves); block does 2 row-tiles of 32 rows.
// Wave w owns 32 rows x 64 cols per chunk (2rt x 4ct fragments of 16x16x32),
// 4 chunks cover N=2048. B: global->reg from packed BP (L2-hot, 1KB coalesced
// loads, no LDS, no barriers in the K-loop). A: 32KB LDS, staged once per tile.
// Softmax: EXACT row-max subtraction (fp32 logits in registers). The data has a
// common-mode row shift (centers mean 0.5 => logit rows shift by ~0.5*sum(x_b));
// without max-subtract, whole rows underflow fp32 exp -> sum==0 -> nan (R5/R6).
// After max-subtract, ssum >= 1 by construction: nan structurally impossible.
__global__ __launch_bounds__(512, 2) void fused_kernel(
    const float* __restrict__ X,       // [BATCH][DIM] fp32
    const _Float16* __restrict__ BP,   // packed B fragments (2 MB)
    const float* __restrict__ hcsq,    // [NCLS] 0.5*||c||^2
    float* __restrict__ O)             // [BATCH][NCLS]
{
    __shared__ __align__(16) _Float16 As[32 * 512];   // 32 KB, granule-swizzled
    __shared__ float redm[8][32];
    __shared__ float rsum[8][32];

    const int tid  = threadIdx.x;
    const int lane = tid & 63;
    const int wave = tid >> 6;
    const int l4   = lane >> 4;     // 16-lane group 0..3
    const int r15  = lane & 15;

    for (int tile = 0; tile < 2; ++tile) {
        const int rowB = (blockIdx.x * 2 + tile) * 32;

        // ---- stage A: fp32 -> fp16, 16B granules XOR-swizzled (slot = g ^ (row&7)) ----
        #pragma unroll
        for (int i = 0; i < 4; ++i) {
            int G = i * 512 + tid;              // 2048 granules = 32 rows x 64
            int row = G >> 6, g = G & 63;
            const float* src = X + (size_t)(rowB + row) * DIM + g * 8;
            float4 a = *reinterpret_cast<const float4*>(src);
            float4 b = *reinterpret_cast<const float4*>(src + 4);
            half8 h;
            h[0] = (_Float16)a.x; h[1] = (_Float16)a.y; h[2] = (_Float16)a.z; h[3] = (_Float16)a.w;
            h[4] = (_Float16)b.x; h[5] = (_Float16)b.y; h[6] = (_Float16)b.z; h[7] = (_Float16)b.w;
            *reinterpret_cast<half8*>(&As[(row * 64 + (g ^ (row & 7))) * 8]) = h;
        }
        __syncthreads();

        floatx4 logv[4][2][4];              // fp32 logits [chunk][rt][ct]
        float mj[2][4];                     // running per-(rt,j) max over owned cols
        #pragma unroll
        for (int rt = 0; rt < 2; ++rt)
            #pragma unroll
            for (int j = 0; j < 4; ++j) mj[rt][j] = -1e30f;

        #pragma unroll
        for (int chunk = 0; chunk < 4; ++chunk) {
            floatx4 acc[2][4];
            #pragma unroll
            for (int rt = 0; rt < 2; ++rt)
                #pragma unroll
                for (int ct = 0; ct < 4; ++ct)
                    acc[rt][ct] = (floatx4){0.f, 0.f, 0.f, 0.f};

            float hc[4];
            #pragma unroll
            for (int ct = 0; ct < 4; ++ct)
                hc[ct] = hcsq[chunk * 512 + wave * 64 + ct * 16 + r15];

            // n(ct) = chunk*32 + wave*4 + ct ; granule = (n*16 + s)*64 + lane
            const _Float16* bb = BP + ((size_t)(chunk * 32 + wave * 4) * 1024 + lane) * 8;

            #pragma unroll 4
            for (int s = 0; s < 16; ++s) {
                half8 bf[4];
                #pragma unroll
                for (int ct = 0; ct < 4; ++ct)
                    bf[ct] = *reinterpret_cast<const half8*>(
                        bb + (size_t)((ct * 16 + s) * 64) * 8);
                const int kg = s * 4 + l4;          // A k-granule
                const int sw = kg ^ (r15 & 7);
                half8 af0 = *reinterpret_cast<const half8*>(&As[(r15 * 64 + sw) * 8]);
                half8 af1 = *reinterpret_cast<const half8*>(&As[((16 + r15) * 64 + sw) * 8]);
                #pragma unroll
                for (int ct = 0; ct < 4; ++ct) {
                    acc[0][ct] = __builtin_amdgcn_mfma_f32_16x16x32_f16(af0, bf[ct], acc[0][ct], 0, 0, 0);
                    acc[1][ct] = __builtin_amdgcn_mfma_f32_16x16x32_f16(af1, bf[ct], acc[1][ct], 0, 0, 0);
                }
            }

            // chunk epilogue: logits = cross - 0.5csq; track running max
            #pragma unroll
            for (int rt = 0; rt < 2; ++rt)
                #pragma unroll
                for (int ct = 0; ct < 4; ++ct) {
                    floatx4 v = acc[rt][ct];
                    #pragma unroll
                    for (int j = 0; j < 4; ++j) {
                        v[j] -= hc[ct];
                        mj[rt][j] = fmaxf(mj[rt][j], v[j]);
                    }
                    logv[chunk][rt][ct] = v;
                }
        }

        // ---- stage 1: exact row max (butterfly over 16-lane group + cross-wave LDS) ----
        #pragma unroll
        for (int off = 8; off >= 1; off >>= 1)
            #pragma unroll
            for (int rt = 0; rt < 2; ++rt)
                #pragma unroll
                for (int j = 0; j < 4; ++j)
                    mj[rt][j] = fmaxf(mj[rt][j], __shfl_xor(mj[rt][j], off));
        if (r15 == 0) {
            #pragma unroll
            for (int rt = 0; rt < 2; ++rt)
                #pragma unroll
                for (int j = 0; j < 4; ++j)
                    redm[wave][rt * 16 + l4 * 4 + j] = mj[rt][j];
        }
        __syncthreads();

        float M[2][4];
        #pragma unroll
        for (int rt = 0; rt < 2; ++rt)
            #pragma unroll
            for (int j = 0; j < 4; ++j) {
                const int r = rt * 16 + l4 * 4 + j;
                float m = redm[0][r];
                #pragma unroll
                for (int w = 1; w < 8; ++w) m = fmaxf(m, redm[w][r]);
                M[rt][j] = m;
            }

        // ---- stage 2: exp + row sum ----
        float tot[2][4];
        #pragma unroll
        for (int rt = 0; rt < 2; ++rt)
            #pragma unroll
            for (int j = 0; j < 4; ++j) tot[rt][j] = 0.f;
        #pragma unroll
        for (int chunk = 0; chunk < 4; ++chunk)
            #pragma unroll
            for (int rt = 0; rt < 2; ++rt)
                #pragma unroll
                for (int ct = 0; ct < 4; ++ct)
                    #pragma unroll
                    for (int j = 0; j < 4; ++j) {
                        float e = __expf(logv[chunk][rt][ct][j] - M[rt][j]);
                        logv[chunk][rt][ct][j] = e;
                        tot[rt][j] += e;
                    }
        #pragma unroll
        for (int off = 8; off >= 1; off >>= 1)
            #pragma unroll
            for (int rt = 0; rt < 2; ++rt)
                #pragma unroll
                for (int j = 0; j < 4; ++j)
                    tot[rt][j] += __shfl_xor(tot[rt][j], off);
        if (r15 == 0) {
            #pragma unroll
            for (int rt = 0; rt < 2; ++rt)
                #pragma unroll
                for (int j = 0; j < 4; ++j)
                    rsum[wave][rt * 16 + l4 * 4 + j] = tot[rt][j];
        }
        __syncthreads();

        float inv[2][4];
        #pragma unroll
        for (int rt = 0; rt < 2; ++rt)
            #pragma unroll
            for (int j = 0; j < 4; ++j) {
                const int r = rt * 16 + l4 * 4 + j;
                float ssum = 0.f;
                #pragma unroll
                for (int w = 0; w < 8; ++w) ssum += rsum[w][r];
                inv[rt][j] = 1.0f / ssum;   // >= 1 term is exp(0)=1: never 0
            }

        // ---- single write of normalized output (C/D: col=r15, row=l4*4+j) ----
        #pragma unroll
        for (int chunk = 0; chunk < 4; ++chunk)
            #pragma unroll
            for (int rt = 0; rt < 2; ++rt)
                #pragma unroll
                for (int ct = 0; ct < 4; ++ct) {
                    const int col = chunk * 512 + wave * 64 + ct * 16 + r15;
                    float* op = O + (size_t)(rowB + rt * 16 + l4 * 4) * NCLS + col;
                    #pragma unroll
                    for (int j = 0; j < 4; ++j)
                        op[(size_t)j * NCLS] = logv[chunk][rt][ct][j] * inv[rt][j];
                }
        __syncthreads();   // As/redm/rsum safe to overwrite for next tile
    }
}

extern "C" void kernel_launch(void* const* d_in, const int* in_sizes, int n_in,
                              void* d_out, int out_size, void* d_ws, size_t ws_size,
                              hipStream_t stream) {
    const float* x       = (const float*)d_in[0];
    const float* centers = (const float*)d_in[1];
    float* out = (float*)d_out;

    // ws layout: BP packed fp16 [128*16*64*8] (2 MB) | 0.5*csq [NCLS] (8 KB)
    _Float16* bp = (_Float16*)d_ws;
    float* hcsq  = (float*)(bp + (size_t)128 * 16 * 64 * 8);

    hipLaunchKernelGGL(pack_b, dim3(128 * 16 * 64 / 256), dim3(256), 0, stream, centers, bp);
    hipLaunchKernelGGL(csq_kernel, dim3(NCLS), dim3(64), 0, stream, centers, hcsq);
    hipLaunchKernelGGL(fused_kernel, dim3(BATCH / 64), dim3(512), 0, stream,
                       x, bp, hcsq, out);
}